// Round 8
// baseline (348.694 us; speedup 1.0000x reference)
//
#include <hip/hip_runtime.h>
#include <hip/hip_bf16.h>
#include <hip/hip_fp16.h>

// Edge-MLP: score[e] = W3·relu(W2·relu(W1u·h[src[e]] + W1v·h[dst[e]] + b1) + b2) + b3
// R8: same compute structure as verified v3 (32x32x16, W in registers, lane-local
// layer-3), but TE=32 / BLOCK=256 / LDS=40960B exactly -> 4 blocks/CU (was 1),
// __launch_bounds__(256,4). Spart aliases Xlds head (extra lgkm barrier covers it).
// X1 epilogue packed to ds_write_b64. Gather DMA double-buffer unchanged.

#define N_NODES 100000
#define N_EDGES 500000
#define F       128
#define HID     128
#define TE      32
#define NT      (N_EDGES / TE)               // 15625, exact
#define GRID    1024
#define BLOCK   256                          // 4 waves = 4 mh blocks

typedef _Float16 f16x8  __attribute__((ext_vector_type(8)));
typedef float    f32x16 __attribute__((ext_vector_type(16)));

typedef __attribute__((address_space(3))) unsigned int  lds_u32;
typedef __attribute__((address_space(1))) const unsigned int glb_u32;

__device__ __forceinline__ void load_lds16(const void* g, void* l) {
    __builtin_amdgcn_global_load_lds((glb_u32*)g, (lds_u32*)l, 16, 0, 0);
}
__device__ __forceinline__ void bar_lgkm() {
    asm volatile("s_waitcnt lgkmcnt(0)" ::: "memory");
    __builtin_amdgcn_s_barrier();
    __builtin_amdgcn_sched_barrier(0);
}
__device__ __forceinline__ void bar_vm() {
    asm volatile("s_waitcnt vmcnt(0) lgkmcnt(0)" ::: "memory");
    __builtin_amdgcn_s_barrier();
    __builtin_amdgcn_sched_barrier(0);
}

// ---------------- h -> f16 conversion pass ----------------
__global__ __launch_bounds__(256) void h_to_f16(const float* __restrict__ h,
                                                _Float16* __restrict__ h16) {
    const int i = (blockIdx.x * 256 + threadIdx.x) * 8;   // 12.8M elems exact
    float4 a = *(const float4*)(h + i);
    float4 b = *(const float4*)(h + i + 4);
    f16x8 v;
    v[0] = (_Float16)a.x; v[1] = (_Float16)a.y; v[2] = (_Float16)a.z; v[3] = (_Float16)a.w;
    v[4] = (_Float16)b.x; v[5] = (_Float16)b.y; v[6] = (_Float16)b.z; v[7] = (_Float16)b.w;
    *(f16x8*)(h16 + i) = v;
}

// ---------------- fused edge kernel, v4 ----------------
__global__ __launch_bounds__(BLOCK, 4) void edge_mlp_v4(
    const _Float16* __restrict__ h16,
    const int*   __restrict__ src,
    const int*   __restrict__ dst,
    const float* __restrict__ W1,   // [128][256]
    const float* __restrict__ b1,
    const float* __restrict__ W2,   // [128][128]
    const float* __restrict__ b2,
    const float* __restrict__ W3,   // [1][128]
    const float* __restrict__ b3,
    float*       __restrict__ out)
{
    // A tiles: 2 x [32 e][256 k] f16, swizzle byte^=((e&15)<<4). 2x16KB.
    __shared__ __align__(128) char Alds[2 * TE * 512];
    // X tile: [32 e][128 hid] f16, same swizzle. 8KB. Spart aliases bytes 0..511.
    __shared__ __align__(128) char Xlds[TE * 256];
    float* Spart = (float*)Xlds;             // [4][32], alias (barrier-protected)

    const int tid  = threadIdx.x;
    const int wave = tid >> 6;               // = mh, 0..3
    const int lane = tid & 63;
    const int mh   = wave;
    const int col  = lane & 31;              // W row within mh block / edge col
    const int h    = lane >> 5;              // k-half

    // ---- weight slices into registers ----
    // A-operand (32x32x16 f16): lane holds A[row=lane&31][k=8*(lane>>5)+j]
    f16x8 w1a[16];
    #pragma unroll
    for (int kt = 0; kt < 16; ++kt) {
        const float* p = W1 + (mh * 32 + col) * 256 + kt * 16 + 8 * h;
        f16x8 v;
        #pragma unroll
        for (int j = 0; j < 8; ++j) v[j] = (_Float16)p[j];
        w1a[kt] = v;
    }
    f16x8 w2a[8];
    #pragma unroll
    for (int kt = 0; kt < 8; ++kt) {
        const float* p = W2 + (mh * 32 + col) * 128 + kt * 16 + 8 * h;
        f16x8 v;
        #pragma unroll
        for (int j = 0; j < 8; ++j) v[j] = (_Float16)p[j];
        w2a[kt] = v;
    }
    // per-lane row tables: row(r) = mh*32 + (r&3) + 8*(r>>2) + 4h
    float b1pl[16], b2pl[16], w3pl[16];
    #pragma unroll
    for (int r = 0; r < 16; ++r) {
        const int row = mh * 32 + (r & 3) + 8 * (r >> 2) + 4 * h;
        b1pl[r] = b1[row];
        b2pl[r] = b2[row];
        w3pl[r] = W3[row];
    }
    const float b3v = b3[0];

    // ---- gather geometry (DMA instr i = wave*4+j, i<16; lane l -> byte i*1024+l*16)
    //   row e = 2i + (l>>5) in 0..31; in-row chunk = l&31
    //   logical chunk = (l&31) ^ (e&15): bit4 (src/dst) untouched ->
    //   which = (l>>4)&1; k16 = (l&15) ^ (e&15)
    int eloc[4], k16v[4];
    #pragma unroll
    for (int j = 0; j < 4; ++j) {
        const int i = wave * 4 + j;
        eloc[j] = 2 * i + h;
        k16v[j] = (lane & 15) ^ (eloc[j] & 15);
    }
    const int whichv = (lane >> 4) & 1;
    const int* idxp  = whichv ? dst : src;

    const int t0 = blockIdx.x;
    int nodeCur[4], nodeNext[4];

    #pragma unroll
    for (int j = 0; j < 4; ++j) {
        nodeCur[j] = idxp[t0 * TE + eloc[j]];            // NT*TE == N_EDGES, no tail
    }
    #pragma unroll
    for (int j = 0; j < 4; ++j) {
        const _Float16* g = h16 + (size_t)nodeCur[j] * F + k16v[j] * 8;
        load_lds16(g, Alds + (wave * 4 + j) * 1024);
    }
    {
        int tn = t0 + GRID; if (tn > NT - 1) tn = NT - 1;
        #pragma unroll
        for (int j = 0; j < 4; ++j) nodeNext[j] = idxp[tn * TE + eloc[j]];
    }

    const int e_own = col;                               // this lane's edge column
    const int exor  = (e_own & 15) << 4;

    int cur = 0;
    for (int t = t0; t < NT; t += GRID) {
        bar_vm();                                        // tile's DMA landed everywhere

        // issue next tile's gather (in flight across whole compute)
        #pragma unroll
        for (int j = 0; j < 4; ++j) nodeCur[j] = nodeNext[j];
        {
            char* nb = Alds + (cur ^ 1) * (TE * 512);
            #pragma unroll
            for (int j = 0; j < 4; ++j) {
                const _Float16* g = h16 + (size_t)nodeCur[j] * F + k16v[j] * 8;
                load_lds16(g, nb + (wave * 4 + j) * 1024);
            }
        }
        {
            int tn2 = t + 2 * GRID; if (tn2 > NT - 1) tn2 = NT - 1;
            #pragma unroll
            for (int j = 0; j < 4; ++j) nodeNext[j] = idxp[tn2 * TE + eloc[j]];
        }

        const char* Ab = Alds + cur * (TE * 512);

        // ---------------- layer 1: X1^T[mh-block][e] = relu(W1 A^T + b1) ----------
        f32x16 acc1 = {};
        #pragma unroll
        for (int kt = 0; kt < 16; ++kt) {
            const int c = (kt * 32 + 16 * h) ^ exor;
            f16x8 bf = *(const f16x8*)(Ab + e_own * 512 + c);
            acc1 = __builtin_amdgcn_mfma_f32_32x32x16_f16(w1a[kt], bf, acc1, 0, 0, 0);
        }
        // epilogue: bias+relu, pack 4-row groups, ds_write_b64
        // group g covers accs r=4g..4g+3 -> rows mh*32 + 8g + 4h + 0..3
        #pragma unroll
        for (int g = 0; g < 4; ++g) {
            union { _Float16 q[4]; unsigned long long u; } pk;
            #pragma unroll
            for (int q = 0; q < 4; ++q) {
                float v = acc1[4 * g + q] + b1pl[4 * g + q];
                v = v > 0.f ? v : 0.f;
                pk.q[q] = (_Float16)v;
            }
            const int c = (mh * 64 + 16 * g + 8 * h) ^ exor;   // 8-B aligned (XOR bits 4-7)
            *(unsigned long long*)(Xlds + e_own * 256 + c) = pk.u;
        }
        bar_lgkm();                                      // X1 visible

        // ---------------- layer 2: X2^T[mh-block][e] (registers) ------------------
        f32x16 acc2 = {};
        #pragma unroll
        for (int kt = 0; kt < 8; ++kt) {
            const int c = (kt * 32 + 16 * h) ^ exor;
            f16x8 xf = *(const f16x8*)(Xlds + e_own * 256 + c);
            acc2 = __builtin_amdgcn_mfma_f32_32x32x16_f16(w2a[kt], xf, acc2, 0, 0, 0);
        }

        // ---------------- layer 3: lane-local dot over this wave's 32 hid rows ----
        float p = 0.f;
        #pragma unroll
        for (int r = 0; r < 16; ++r) {
            float v = acc2[r] + b2pl[r];
            v = v > 0.f ? v : 0.f;
            p = fmaf(w3pl[r], v, p);
        }
        p += __shfl_xor(p, 32);                          // both k-halves -> 32 rows

        bar_lgkm();                                      // all X reads done (Spart alias!)
        if (lane < 32) Spart[wave * 32 + lane] = p;
        bar_lgkm();                                      // Spart visible

        if (tid < TE) {
            float s = Spart[tid] + Spart[32 + tid] + Spart[64 + tid]
                    + Spart[96 + tid] + b3v;
            out[t * TE + tid] = s;
        }
        cur ^= 1;
        // next bar_vm gates A-buf DMA reuse and X1 rewrite vs Spart reads
    }
}

// ---------------- fallback (round-1 proven kernel) ----------------
__global__ __launch_bounds__(512) void edge_mlp_v1(
    const float* __restrict__ h,
    const int*   __restrict__ src,
    const int*   __restrict__ dst,
    const float* __restrict__ W1,
    const float* __restrict__ b1,
    const float* __restrict__ W2,
    const float* __restrict__ b2,
    const float* __restrict__ W3,
    const float* __restrict__ b3,
    float*       __restrict__ out)
{
    __shared__ __align__(128) char Alds[64 * 512];
    __shared__ __align__(128) char Xlds[64 * 256];
    typedef float f32x4 __attribute__((ext_vector_type(4)));

    const int tid  = threadIdx.x;
    const int wave = tid >> 6;
    const int lane = tid & 63;
    const int l15  = lane & 15;
    const int lk   = lane >> 4;
    const int n1 = wave * 16 + l15;
    const int NT1 = (N_EDGES + 63) / 64;

    f16x8 w1f[8];
    #pragma unroll
    for (int kt = 0; kt < 8; ++kt) {
        const float* p = W1 + n1 * 256 + kt * 32 + lk * 8;
        f16x8 v;
        #pragma unroll
        for (int j = 0; j < 8; ++j) v[j] = (_Float16)p[j];
        w1f[kt] = v;
    }
    const float b1v = b1[n1];
    f16x8 w2f[4];
    #pragma unroll
    for (int kt = 0; kt < 4; ++kt) {
        const float* p = W2 + n1 * 128 + kt * 32 + lk * 8;
        f16x8 v;
        #pragma unroll
        for (int j = 0; j < 8; ++j) v[j] = (_Float16)p[j];
        w2f[kt] = v;
    }
    const float b2v = b2[n1];
    float w3r[16];
    {
        const float* p = W3 + (tid & 7) * 16;
        #pragma unroll
        for (int i = 0; i < 16; ++i) w3r[i] = p[i];
    }
    const float b3v = b3[0];

    const int slot = tid >> 2, part = tid & 3;
    const int g_e = slot >> 1, g_which = slot & 1;

    for (int t = blockIdx.x; t < NT1; t += gridDim.x) {
        {
            int eg = t * 64 + g_e;
            if (eg >= N_EDGES) eg = N_EDGES - 1;
            const int node = g_which ? dst[eg] : src[eg];
            const float* p = h + node * F + part * 32;
            const int kbase = g_which * 128 + part * 32;
            #pragma unroll
            for (int c = 0; c < 4; ++c) {
                float4 v0 = *(const float4*)(p + c * 8);
                float4 v1 = *(const float4*)(p + c * 8 + 4);
                f16x8 x;
                x[0] = (_Float16)v0.x; x[1] = (_Float16)v0.y;
                x[2] = (_Float16)v0.z; x[3] = (_Float16)v0.w;
                x[4] = (_Float16)v1.x; x[5] = (_Float16)v1.y;
                x[6] = (_Float16)v1.z; x[7] = (_Float16)v1.w;
                int byte = g_e * 512 + (kbase + c * 8) * 2;
                byte ^= (g_e & 7) << 4;
                *(f16x8*)(Alds + byte) = x;
            }
        }
        __syncthreads();
        #pragma unroll
        for (int m = 0; m < 4; ++m) {
            f32x4 acc = {0.f, 0.f, 0.f, 0.f};
            #pragma unroll
            for (int kt = 0; kt < 8; ++kt) {
                const int edge = m * 16 + l15;
                int byte = edge * 512 + (kt * 32 + lk * 8) * 2;
                byte ^= (edge & 7) << 4;
                f16x8 a = *(const f16x8*)(Alds + byte);
                acc = __builtin_amdgcn_mfma_f32_16x16x32_f16(a, w1f[kt], acc, 0, 0, 0);
            }
            #pragma unroll
            for (int r = 0; r < 4; ++r) {
                float v = acc[r] + b1v;
                v = v > 0.f ? v : 0.f;
                const int edge = m * 16 + lk * 4 + r;
                int byte = edge * 256 + n1 * 2;
                byte ^= (edge & 7) << 4;
                *(_Float16*)(Xlds + byte) = (_Float16)v;
            }
        }
        __syncthreads();
        f32x4 acc2[4];
        #pragma unroll
        for (int m = 0; m < 4; ++m) {
            f32x4 acc = {0.f, 0.f, 0.f, 0.f};
            #pragma unroll
            for (int kt = 0; kt < 4; ++kt) {
                const int edge = m * 16 + l15;
                int byte = edge * 256 + (kt * 32 + lk * 8) * 2;
                byte ^= (edge & 7) << 4;
                f16x8 a = *(const f16x8*)(Xlds + byte);
                acc = __builtin_amdgcn_mfma_f32_16x16x32_f16(a, w2f[kt], acc, 0, 0, 0);
            }
            acc2[m] = acc;
        }
        __syncthreads();
        #pragma unroll
        for (int m = 0; m < 4; ++m) {
            #pragma unroll
            for (int r = 0; r < 4; ++r) {
                float v = acc2[m][r] + b2v;
                v = v > 0.f ? v : 0.f;
                const int edge = m * 16 + lk * 4 + r;
                int byte = edge * 256 + n1 * 2;
                byte ^= (edge & 7) << 4;
                *(_Float16*)(Xlds + byte) = (_Float16)v;
            }
        }
        __syncthreads();
        {
            const int e_loc = tid >> 3;
            const int cgrp  = tid & 7;
            const int swz   = (e_loc & 7) << 4;
            const int base  = e_loc * 256 + cgrp * 32;
            f16x8 x0 = *(const f16x8*)(Xlds + (base ^ swz));
            f16x8 x1 = *(const f16x8*)(Xlds + ((base + 16) ^ swz));
            float p = 0.f;
            #pragma unroll
            for (int i = 0; i < 8; ++i) p += (float)x0[i] * w3r[i];
            #pragma unroll
            for (int i = 0; i < 8; ++i) p += (float)x1[i] * w3r[8 + i];
            p += __shfl_xor(p, 1);
            p += __shfl_xor(p, 2);
            p += __shfl_xor(p, 4);
            const int eg = t * 64 + e_loc;
            if (cgrp == 0 && eg < N_EDGES) out[eg] = p + b3v;
        }
    }
}

extern "C" void kernel_launch(void* const* d_in, const int* in_sizes, int n_in,
                              void* d_out, int out_size, void* d_ws, size_t ws_size,
                              hipStream_t stream) {
    const float* h   = (const float*)d_in[0];
    const int*   src = (const int*)  d_in[1];
    const int*   dst = (const int*)  d_in[2];
    const float* W1  = (const float*)d_in[3];
    const float* b1  = (const float*)d_in[4];
    const float* W2  = (const float*)d_in[5];
    const float* b2  = (const float*)d_in[6];
    const float* W3  = (const float*)d_in[7];
    const float* b3  = (const float*)d_in[8];
    float* out = (float*)d_out;

    const size_t need = (size_t)N_NODES * F * sizeof(_Float16);   // 25.6 MB
    if (ws_size >= need) {
        _Float16* h16 = (_Float16*)d_ws;
        h_to_f16<<<6250, 256, 0, stream>>>(h, h16);
        edge_mlp_v4<<<GRID, BLOCK, 0, stream>>>(h16, src, dst, W1, b1, W2, b2, W3, b3, out);
    } else {
        edge_mlp_v1<<<512, 512, 0, stream>>>(h, src, dst, W1, b1, W2, b2, W3, b3, out);
    }
}

// Round 10
// 188.390 us; speedup vs baseline: 1.8509x; 1.8509x over previous
//
#include <hip/hip_runtime.h>
#include <hip/hip_bf16.h>
#include <hip/hip_fp16.h>

// Edge-MLP: score[e] = W3·relu(W2·relu(W1u·h[src[e]] + W1v·h[dst[e]] + b1) + b2) + b3
// R10 (= R9 resubmitted; infra failed): TE=32 / BLOCK=256 / LDS=40960B -> up to
// 4 blocks/CU by LDS; __launch_bounds__(256) WITHOUT min-waves so the compiler
// allocates the ~112 VGPRs the weights-in-registers scheme needs (R8's (256,4)
// forced 64 VGPR -> 91MB spill writes + 805MB spill reads -> 258us regression).
// Compute structure HW-verified (v3 94.6us / v4-spilled both passed, absmax equal).

#define N_NODES 100000
#define N_EDGES 500000
#define F       128
#define HID     128
#define TE      32
#define NT      (N_EDGES / TE)               // 15625, exact
#define GRID    1024
#define BLOCK   256                          // 4 waves = 4 mh blocks

typedef _Float16 f16x8  __attribute__((ext_vector_type(8)));
typedef float    f32x16 __attribute__((ext_vector_type(16)));

typedef __attribute__((address_space(3))) unsigned int  lds_u32;
typedef __attribute__((address_space(1))) const unsigned int glb_u32;

__device__ __forceinline__ void load_lds16(const void* g, void* l) {
    __builtin_amdgcn_global_load_lds((glb_u32*)g, (lds_u32*)l, 16, 0, 0);
}
__device__ __forceinline__ void bar_lgkm() {
    asm volatile("s_waitcnt lgkmcnt(0)" ::: "memory");
    __builtin_amdgcn_s_barrier();
    __builtin_amdgcn_sched_barrier(0);
}
__device__ __forceinline__ void bar_vm() {
    asm volatile("s_waitcnt vmcnt(0) lgkmcnt(0)" ::: "memory");
    __builtin_amdgcn_s_barrier();
    __builtin_amdgcn_sched_barrier(0);
}

// ---------------- h -> f16 conversion pass ----------------
__global__ __launch_bounds__(256) void h_to_f16(const float* __restrict__ h,
                                                _Float16* __restrict__ h16) {
    const int i = (blockIdx.x * 256 + threadIdx.x) * 8;   // 12.8M elems exact
    float4 a = *(const float4*)(h + i);
    float4 b = *(const float4*)(h + i + 4);
    f16x8 v;
    v[0] = (_Float16)a.x; v[1] = (_Float16)a.y; v[2] = (_Float16)a.z; v[3] = (_Float16)a.w;
    v[4] = (_Float16)b.x; v[5] = (_Float16)b.y; v[6] = (_Float16)b.z; v[7] = (_Float16)b.w;
    *(f16x8*)(h16 + i) = v;
}

// ---------------- fused edge kernel, v4b ----------------
__global__ __launch_bounds__(BLOCK) void edge_mlp_v4(
    const _Float16* __restrict__ h16,
    const int*   __restrict__ src,
    const int*   __restrict__ dst,
    const float* __restrict__ W1,   // [128][256]
    const float* __restrict__ b1,
    const float* __restrict__ W2,   // [128][128]
    const float* __restrict__ b2,
    const float* __restrict__ W3,   // [1][128]
    const float* __restrict__ b3,
    float*       __restrict__ out)
{
    // A tiles: 2 x [32 e][256 k] f16, swizzle byte^=((e&15)<<4). 2x16KB.
    __shared__ __align__(128) char Alds[2 * TE * 512];
    // X tile: [32 e][128 hid] f16, same swizzle. 8KB. Spart aliases bytes 0..511.
    __shared__ __align__(128) char Xlds[TE * 256];
    float* Spart = (float*)Xlds;             // [4][32], alias (barrier-protected)

    const int tid  = threadIdx.x;
    const int wave = tid >> 6;               // = mh, 0..3
    const int lane = tid & 63;
    const int mh   = wave;
    const int col  = lane & 31;              // W row within mh block / edge col
    const int h    = lane >> 5;              // k-half

    // ---- weight slices into registers ----
    // A-operand (32x32x16 f16): lane holds A[row=lane&31][k=8*(lane>>5)+j]
    f16x8 w1a[16];
    #pragma unroll
    for (int kt = 0; kt < 16; ++kt) {
        const float* p = W1 + (mh * 32 + col) * 256 + kt * 16 + 8 * h;
        f16x8 v;
        #pragma unroll
        for (int j = 0; j < 8; ++j) v[j] = (_Float16)p[j];
        w1a[kt] = v;
    }
    f16x8 w2a[8];
    #pragma unroll
    for (int kt = 0; kt < 8; ++kt) {
        const float* p = W2 + (mh * 32 + col) * 128 + kt * 16 + 8 * h;
        f16x8 v;
        #pragma unroll
        for (int j = 0; j < 8; ++j) v[j] = (_Float16)p[j];
        w2a[kt] = v;
    }
    // per-lane row tables: row(r) = mh*32 + (r&3) + 8*(r>>2) + 4h
    float b1pl[16], b2pl[16], w3pl[16];
    #pragma unroll
    for (int r = 0; r < 16; ++r) {
        const int row = mh * 32 + (r & 3) + 8 * (r >> 2) + 4 * h;
        b1pl[r] = b1[row];
        b2pl[r] = b2[row];
        w3pl[r] = W3[row];
    }
    const float b3v = b3[0];

    // ---- gather geometry (DMA instr i = wave*4+j, i<16; lane l -> byte i*1024+l*16)
    //   row e = 2i + (l>>5) in 0..31; in-row chunk = l&31
    //   logical chunk = (l&31) ^ (e&15): bit4 (src/dst) untouched ->
    //   which = (l>>4)&1; k16 = (l&15) ^ (e&15)
    int eloc[4], k16v[4];
    #pragma unroll
    for (int j = 0; j < 4; ++j) {
        const int i = wave * 4 + j;
        eloc[j] = 2 * i + h;
        k16v[j] = (lane & 15) ^ (eloc[j] & 15);
    }
    const int whichv = (lane >> 4) & 1;
    const int* idxp  = whichv ? dst : src;

    const int t0 = blockIdx.x;
    int nodeCur[4], nodeNext[4];

    #pragma unroll
    for (int j = 0; j < 4; ++j) {
        nodeCur[j] = idxp[t0 * TE + eloc[j]];            // NT*TE == N_EDGES, no tail
    }
    #pragma unroll
    for (int j = 0; j < 4; ++j) {
        const _Float16* g = h16 + (size_t)nodeCur[j] * F + k16v[j] * 8;
        load_lds16(g, Alds + (wave * 4 + j) * 1024);
    }
    {
        int tn = t0 + GRID; if (tn > NT - 1) tn = NT - 1;
        #pragma unroll
        for (int j = 0; j < 4; ++j) nodeNext[j] = idxp[tn * TE + eloc[j]];
    }

    const int e_own = col;                               // this lane's edge column
    const int exor  = (e_own & 15) << 4;

    int cur = 0;
    for (int t = t0; t < NT; t += GRID) {
        bar_vm();                                        // tile's DMA landed everywhere

        // issue next tile's gather (in flight across whole compute)
        #pragma unroll
        for (int j = 0; j < 4; ++j) nodeCur[j] = nodeNext[j];
        {
            char* nb = Alds + (cur ^ 1) * (TE * 512);
            #pragma unroll
            for (int j = 0; j < 4; ++j) {
                const _Float16* g = h16 + (size_t)nodeCur[j] * F + k16v[j] * 8;
                load_lds16(g, nb + (wave * 4 + j) * 1024);
            }
        }
        {
            int tn2 = t + 2 * GRID; if (tn2 > NT - 1) tn2 = NT - 1;
            #pragma unroll
            for (int j = 0; j < 4; ++j) nodeNext[j] = idxp[tn2 * TE + eloc[j]];
        }

        const char* Ab = Alds + cur * (TE * 512);

        // ---------------- layer 1: X1^T[mh-block][e] = relu(W1 A^T + b1) ----------
        f32x16 acc1 = {};
        #pragma unroll
        for (int kt = 0; kt < 16; ++kt) {
            const int c = (kt * 32 + 16 * h) ^ exor;
            f16x8 bf = *(const f16x8*)(Ab + e_own * 512 + c);
            acc1 = __builtin_amdgcn_mfma_f32_32x32x16_f16(w1a[kt], bf, acc1, 0, 0, 0);
        }
        // epilogue: bias+relu, pack 4-row groups, ds_write_b64
        // group g covers accs r=4g..4g+3 -> rows mh*32 + 8g + 4h + 0..3
        #pragma unroll
        for (int g = 0; g < 4; ++g) {
            union { _Float16 q[4]; unsigned long long u; } pk;
            #pragma unroll
            for (int q = 0; q < 4; ++q) {
                float v = acc1[4 * g + q] + b1pl[4 * g + q];
                v = v > 0.f ? v : 0.f;
                pk.q[q] = (_Float16)v;
            }
            const int c = (mh * 64 + 16 * g + 8 * h) ^ exor;   // 8-B aligned (XOR bits 4-7)
            *(unsigned long long*)(Xlds + e_own * 256 + c) = pk.u;
        }
        bar_lgkm();                                      // X1 visible

        // ---------------- layer 2: X2^T[mh-block][e] (registers) ------------------
        f32x16 acc2 = {};
        #pragma unroll
        for (int kt = 0; kt < 8; ++kt) {
            const int c = (kt * 32 + 16 * h) ^ exor;
            f16x8 xf = *(const f16x8*)(Xlds + e_own * 256 + c);
            acc2 = __builtin_amdgcn_mfma_f32_32x32x16_f16(w2a[kt], xf, acc2, 0, 0, 0);
        }

        // ---------------- layer 3: lane-local dot over this wave's 32 hid rows ----
        float p = 0.f;
        #pragma unroll
        for (int r = 0; r < 16; ++r) {
            float v = acc2[r] + b2pl[r];
            v = v > 0.f ? v : 0.f;
            p = fmaf(w3pl[r], v, p);
        }
        p += __shfl_xor(p, 32);                          // both k-halves -> 32 rows

        bar_lgkm();                                      // all X reads done (Spart alias!)
        if (lane < 32) Spart[wave * 32 + lane] = p;
        bar_lgkm();                                      // Spart visible

        if (tid < TE) {
            float s = Spart[tid] + Spart[32 + tid] + Spart[64 + tid]
                    + Spart[96 + tid] + b3v;
            out[t * TE + tid] = s;
        }
        cur ^= 1;
        // next bar_vm gates A-buf DMA reuse and X1 rewrite vs Spart reads
    }
}

// ---------------- fallback (round-1 proven kernel) ----------------
__global__ __launch_bounds__(512) void edge_mlp_v1(
    const float* __restrict__ h,
    const int*   __restrict__ src,
    const int*   __restrict__ dst,
    const float* __restrict__ W1,
    const float* __restrict__ b1,
    const float* __restrict__ W2,
    const float* __restrict__ b2,
    const float* __restrict__ W3,
    const float* __restrict__ b3,
    float*       __restrict__ out)
{
    __shared__ __align__(128) char Alds[64 * 512];
    __shared__ __align__(128) char Xlds[64 * 256];
    typedef float f32x4 __attribute__((ext_vector_type(4)));

    const int tid  = threadIdx.x;
    const int wave = tid >> 6;
    const int lane = tid & 63;
    const int l15  = lane & 15;
    const int lk   = lane >> 4;
    const int n1 = wave * 16 + l15;
    const int NT1 = (N_EDGES + 63) / 64;

    f16x8 w1f[8];
    #pragma unroll
    for (int kt = 0; kt < 8; ++kt) {
        const float* p = W1 + n1 * 256 + kt * 32 + lk * 8;
        f16x8 v;
        #pragma unroll
        for (int j = 0; j < 8; ++j) v[j] = (_Float16)p[j];
        w1f[kt] = v;
    }
    const float b1v = b1[n1];
    f16x8 w2f[4];
    #pragma unroll
    for (int kt = 0; kt < 4; ++kt) {
        const float* p = W2 + n1 * 128 + kt * 32 + lk * 8;
        f16x8 v;
        #pragma unroll
        for (int j = 0; j < 8; ++j) v[j] = (_Float16)p[j];
        w2f[kt] = v;
    }
    const float b2v = b2[n1];
    float w3r[16];
    {
        const float* p = W3 + (tid & 7) * 16;
        #pragma unroll
        for (int i = 0; i < 16; ++i) w3r[i] = p[i];
    }
    const float b3v = b3[0];

    const int slot = tid >> 2, part = tid & 3;
    const int g_e = slot >> 1, g_which = slot & 1;

    for (int t = blockIdx.x; t < NT1; t += gridDim.x) {
        {
            int eg = t * 64 + g_e;
            if (eg >= N_EDGES) eg = N_EDGES - 1;
            const int node = g_which ? dst[eg] : src[eg];
            const float* p = h + node * F + part * 32;
            const int kbase = g_which * 128 + part * 32;
            #pragma unroll
            for (int c = 0; c < 4; ++c) {
                float4 v0 = *(const float4*)(p + c * 8);
                float4 v1 = *(const float4*)(p + c * 8 + 4);
                f16x8 x;
                x[0] = (_Float16)v0.x; x[1] = (_Float16)v0.y;
                x[2] = (_Float16)v0.z; x[3] = (_Float16)v0.w;
                x[4] = (_Float16)v1.x; x[5] = (_Float16)v1.y;
                x[6] = (_Float16)v1.z; x[7] = (_Float16)v1.w;
                int byte = g_e * 512 + (kbase + c * 8) * 2;
                byte ^= (g_e & 7) << 4;
                *(f16x8*)(Alds + byte) = x;
            }
        }
        __syncthreads();
        #pragma unroll
        for (int m = 0; m < 4; ++m) {
            f32x4 acc = {0.f, 0.f, 0.f, 0.f};
            #pragma unroll
            for (int kt = 0; kt < 8; ++kt) {
                const int edge = m * 16 + l15;
                int byte = edge * 512 + (kt * 32 + lk * 8) * 2;
                byte ^= (edge & 7) << 4;
                f16x8 a = *(const f16x8*)(Alds + byte);
                acc = __builtin_amdgcn_mfma_f32_16x16x32_f16(a, w1f[kt], acc, 0, 0, 0);
            }
            #pragma unroll
            for (int r = 0; r < 4; ++r) {
                float v = acc[r] + b1v;
                v = v > 0.f ? v : 0.f;
                const int edge = m * 16 + lk * 4 + r;
                int byte = edge * 256 + n1 * 2;
                byte ^= (edge & 7) << 4;
                *(_Float16*)(Xlds + byte) = (_Float16)v;
            }
        }
        __syncthreads();
        f32x4 acc2[4];
        #pragma unroll
        for (int m = 0; m < 4; ++m) {
            f32x4 acc = {0.f, 0.f, 0.f, 0.f};
            #pragma unroll
            for (int kt = 0; kt < 4; ++kt) {
                const int edge = m * 16 + l15;
                int byte = edge * 256 + (kt * 32 + lk * 8) * 2;
                byte ^= (edge & 7) << 4;
                f16x8 a = *(const f16x8*)(Xlds + byte);
                acc = __builtin_amdgcn_mfma_f32_16x16x32_f16(a, w2f[kt], acc, 0, 0, 0);
            }
            acc2[m] = acc;
        }
        __syncthreads();
        #pragma unroll
        for (int m = 0; m < 4; ++m) {
            #pragma unroll
            for (int r = 0; r < 4; ++r) {
                float v = acc2[m][r] + b2v;
                v = v > 0.f ? v : 0.f;
                const int edge = m * 16 + lk * 4 + r;
                int byte = edge * 256 + n1 * 2;
                byte ^= (edge & 7) << 4;
                *(_Float16*)(Xlds + byte) = (_Float16)v;
            }
        }
        __syncthreads();
        {
            const int e_loc = tid >> 3;
            const int cgrp  = tid & 7;
            const int swz   = (e_loc & 7) << 4;
            const int base  = e_loc * 256 + cgrp * 32;
            f16x8 x0 = *(const f16x8*)(Xlds + (base ^ swz));
            f16x8 x1 = *(const f16x8*)(Xlds + ((base + 16) ^ swz));
            float p = 0.f;
            #pragma unroll
            for (int i = 0; i < 8; ++i) p += (float)x0[i] * w3r[i];
            #pragma unroll
            for (int i = 0; i < 8; ++i) p += (float)x1[i] * w3r[8 + i];
            p += __shfl_xor(p, 1);
            p += __shfl_xor(p, 2);
            p += __shfl_xor(p, 4);
            const int eg = t * 64 + e_loc;
            if (cgrp == 0 && eg < N_EDGES) out[eg] = p + b3v;
        }
    }
}

extern "C" void kernel_launch(void* const* d_in, const int* in_sizes, int n_in,
                              void* d_out, int out_size, void* d_ws, size_t ws_size,
                              hipStream_t stream) {
    const float* h   = (const float*)d_in[0];
    const int*   src = (const int*)  d_in[1];
    const int*   dst = (const int*)  d_in[2];
    const float* W1  = (const float*)d_in[3];
    const float* b1  = (const float*)d_in[4];
    const float* W2  = (const float*)d_in[5];
    const float* b2  = (const float*)d_in[6];
    const float* W3  = (const float*)d_in[7];
    const float* b3  = (const float*)d_in[8];
    float* out = (float*)d_out;

    const size_t need = (size_t)N_NODES * F * sizeof(_Float16);   // 25.6 MB
    if (ws_size >= need) {
        _Float16* h16 = (_Float16*)d_ws;
        h_to_f16<<<6250, 256, 0, stream>>>(h, h16);
        edge_mlp_v4<<<GRID, BLOCK, 0, stream>>>(h16, src, dst, W1, b1, W2, b2, W3, b3, out);
    } else {
        edge_mlp_v1<<<512, 512, 0, stream>>>(h, src, dst, W1, b1, W2, b2, W3, b3, out);
    }
}